// Round 2
// baseline (1957.031 us; speedup 1.0000x reference)
//
#include <hip/hip_runtime.h>

#define T_STEPS 1024
#define BATCH   64
#define IDIM    128
#define HDIM    512
#define ALPHA_F 0.02f

typedef _Float16 half2_t __attribute__((ext_vector_type(2)));
typedef unsigned int uint32;

// packed f16 dot2 with f32 accumulate: acc += a.x*b.x + a.y*b.y
__device__ __forceinline__ float dot2f(uint32 w, uint32 h, float acc) {
#if __has_builtin(__builtin_amdgcn_fdot2)
  return __builtin_amdgcn_fdot2(__builtin_bit_cast(half2_t, w),
                                __builtin_bit_cast(half2_t, h), acc, false);
#else
  half2_t a = __builtin_bit_cast(half2_t, w);
  half2_t b = __builtin_bit_cast(half2_t, h);
  return acc + (float)a.x * (float)b.x + (float)a.y * (float)b.y;
#endif
}

__device__ __forceinline__ uint32 pk2(float a, float b) {
  auto p = __builtin_amdgcn_cvt_pkrtz(a, b);  // v2f16 packed, exact type per compiler
  return __builtin_bit_cast(uint32, p);
}

// ---------------------------------------------------------------------------
// x_proj kernel: xp[m][j] = sum_i x[m][i] * Win[j][i],  m in [0, rows)
// thread j holds W_in row j as 64 packed-f16 pairs in registers.
// ---------------------------------------------------------------------------
__global__ __launch_bounds__(512) void ctrnn_proj(
    const float* __restrict__ x,    // [rows][128]
    const float* __restrict__ Win,  // [512][128]
    float* __restrict__ xp,         // [rows][512]
    int rows) {
  const int j = threadIdx.x;
  __shared__ __attribute__((aligned(16))) uint32 xb[8][64];  // 8 rows of x, f16 pairs

  uint32 w[64];
  const float2* wr = (const float2*)(Win + (size_t)j * IDIM);
#pragma unroll
  for (int p = 0; p < 64; ++p) {
    float2 f = wr[p];
    w[p] = pk2(f.x, f.y);
  }

  const int m0 = blockIdx.x * 128;
  for (int it = 0; it < 16; ++it) {
    const int mb = m0 + it * 8;
    __syncthreads();  // protect xb reads of previous iteration
    if (j < 256) {
      const int r = j >> 5, q = j & 31;
      const int m = mb + r;
      float4 v = make_float4(0.f, 0.f, 0.f, 0.f);
      if (m < rows) v = *(const float4*)(x + (size_t)m * IDIM + q * 4);
      xb[r][2 * q]     = pk2(v.x, v.y);
      xb[r][2 * q + 1] = pk2(v.z, v.w);
    }
    __syncthreads();
#pragma unroll
    for (int r = 0; r < 8; ++r) {
      const int m = mb + r;
      if (m < rows) {
        const uint4* xv = (const uint4*)xb[r];
        float a0 = 0.f, a1 = 0.f, a2 = 0.f, a3 = 0.f;
#pragma unroll
        for (int c = 0; c < 16; ++c) {
          uint4 hx = xv[c];
          a0 = dot2f(w[4 * c + 0], hx.x, a0);
          a1 = dot2f(w[4 * c + 1], hx.y, a1);
          a2 = dot2f(w[4 * c + 2], hx.z, a2);
          a3 = dot2f(w[4 * c + 3], hx.w, a3);
        }
        xp[(size_t)m * HDIM + j] = (a0 + a1) + (a2 + a3);
      }
    }
  }
}

// ---------------------------------------------------------------------------
// scan kernel: one block per batch sample, thread j owns hidden unit j.
// W_h row j: cols [0,384) in 192 packed-f16 VGPRs; cols [384,512) in LDS
// (layout [pair-chunk][row] -> conflict-free b64 reads). Hidden state f32 in
// register; f16 mirror double-buffered in LDS, read via broadcast b128.
// ---------------------------------------------------------------------------
__global__ __launch_bounds__(512, 2) void ctrnn_scan(
    const float* __restrict__ xp,  // [ct][BATCH][HDIM] chunk-local
    const float* __restrict__ Wh,  // [512][512]
    const float* __restrict__ h0,  // [512]
    float* __restrict__ out,       // [T][B][H] then [B][H] final hidden
    int t0, int ct) {
  const int b = blockIdx.x;
  const int j = threadIdx.x;

  __shared__ uint2 wlds[32][HDIM];                                 // 128 KB
  __shared__ __attribute__((aligned(16))) _Float16 hbuf[2][HDIM];  // 2 KB

  // register-resident weights: row j, cols [0, 384) as 192 f16 pairs
  uint32 w[192];
  const float2* wr = (const float2*)(Wh + (size_t)j * HDIM);
#pragma unroll
  for (int p = 0; p < 192; ++p) {
    float2 f = wr[p];
    w[p] = pk2(f.x, f.y);
  }
  // LDS-resident weights: row j, cols [384, 512) as 32 x uint2
  {
    const float4* wr4 = (const float4*)(Wh + (size_t)j * HDIM + 384);
#pragma unroll
    for (int p2 = 0; p2 < 32; ++p2) {
      float4 v = wr4[p2];
      wlds[p2][j] = make_uint2(pk2(v.x, v.y), pk2(v.z, v.w));
    }
  }

  // initial hidden state (chunk 0: h0 broadcast; later chunks: prev output)
  float h;
  if (t0 == 0) h = h0[j];
  else h = out[((size_t)(t0 - 1) * BATCH + b) * HDIM + j];
  hbuf[0][j] = (_Float16)h;
  __syncthreads();

  float xp_cur = xp[((size_t)0 * BATCH + b) * HDIM + j];
  int cur = 0;
  for (int t = 0; t < ct; ++t) {
    // prefetch next timestep's input projection (hides HBM latency)
    const int tn = (t + 1 < ct) ? (t + 1) : t;
    const float xp_nxt = xp[((size_t)tn * BATCH + b) * HDIM + j];

    const uint4* hb = (const uint4*)&hbuf[cur][0];
    float a0 = 0.f, a1 = 0.f, a2 = 0.f, a3 = 0.f;
#pragma unroll
    for (int c = 0; c < 48; ++c) {  // cols [0,384): weights from registers
      uint4 hv = hb[c];
      a0 = dot2f(w[4 * c + 0], hv.x, a0);
      a1 = dot2f(w[4 * c + 1], hv.y, a1);
      a2 = dot2f(w[4 * c + 2], hv.z, a2);
      a3 = dot2f(w[4 * c + 3], hv.w, a3);
    }
#pragma unroll
    for (int c = 0; c < 16; ++c) {  // cols [384,512): weights from LDS
      uint4 hv = hb[48 + c];
      uint2 wa = wlds[2 * c][j];
      uint2 wb = wlds[2 * c + 1][j];
      a0 = dot2f(wa.x, hv.x, a0);
      a1 = dot2f(wa.y, hv.y, a1);
      a2 = dot2f(wb.x, hv.z, a2);
      a3 = dot2f(wb.y, hv.w, a3);
    }
    const float z = ((a0 + a1) + (a2 + a3)) + xp_cur;
    const float s = 1.0f / (1.0f + __expf(-z));
    h = h * (1.0f - ALPHA_F) + s * ALPHA_F;

    out[((size_t)(t0 + t) * BATCH + b) * HDIM + j] = h;
    hbuf[cur ^ 1][j] = (_Float16)h;
    __syncthreads();
    cur ^= 1;
    xp_cur = xp_nxt;
  }

  // final hidden state appended after [T,B,H] output
  if (t0 + ct == T_STEPS) {
    out[(size_t)T_STEPS * BATCH * HDIM + (size_t)b * HDIM + j] = h;
  }
}

// ---------------------------------------------------------------------------
extern "C" void kernel_launch(void* const* d_in, const int* in_sizes, int n_in,
                              void* d_out, int out_size, void* d_ws, size_t ws_size,
                              hipStream_t stream) {
  const float* x   = (const float*)d_in[0];
  const float* Win = (const float*)d_in[1];
  const float* Wh  = (const float*)d_in[2];
  const float* h0  = (const float*)d_in[3];
  float* out = (float*)d_out;
  float* xp  = (float*)d_ws;

  // chunk timesteps so xp fits in the workspace (usually one chunk: 128 MB)
  const size_t step_bytes = (size_t)BATCH * HDIM * sizeof(float);  // 128 KB
  int ct_max = (int)(ws_size / step_bytes);
  if (ct_max < 1) ct_max = 1;
  if (ct_max > T_STEPS) ct_max = T_STEPS;

  for (int t0 = 0; t0 < T_STEPS; t0 += ct_max) {
    const int ct = (T_STEPS - t0 < ct_max) ? (T_STEPS - t0) : ct_max;
    const int rows = ct * BATCH;
    const int nb = (rows + 127) / 128;
    hipLaunchKernelGGL(ctrnn_proj, dim3(nb), dim3(512), 0, stream,
                       x + (size_t)t0 * BATCH * IDIM, Win, xp, rows);
    hipLaunchKernelGGL(ctrnn_scan, dim3(BATCH), dim3(512), 0, stream,
                       xp, Wh, h0, out, t0, ct);
  }
}

// Round 3
// 1802.359 us; speedup vs baseline: 1.0858x; 1.0858x over previous
//
#include <hip/hip_runtime.h>

#define T_STEPS 1024
#define BATCH   64
#define IDIM    128
#define HDIM    512
#define ALPHA_F 0.02f

typedef _Float16 half2_t __attribute__((ext_vector_type(2)));
typedef unsigned int uint32;

// packed f16 dot2 with f32 accumulate: acc += a.x*b.x + a.y*b.y
__device__ __forceinline__ float dot2f(uint32 w, uint32 h, float acc) {
#if __has_builtin(__builtin_amdgcn_fdot2)
  return __builtin_amdgcn_fdot2(__builtin_bit_cast(half2_t, w),
                                __builtin_bit_cast(half2_t, h), acc, false);
#else
  half2_t a = __builtin_bit_cast(half2_t, w);
  half2_t b = __builtin_bit_cast(half2_t, h);
  return acc + (float)a.x * (float)b.x + (float)a.y * (float)b.y;
#endif
}

__device__ __forceinline__ uint32 pk2(float a, float b) {
  auto p = __builtin_amdgcn_cvt_pkrtz(a, b);
  return __builtin_bit_cast(uint32, p);
}

// ---------------------------------------------------------------------------
// x_proj kernel: xp[m][j] = sum_i x[m][i] * Win[j][i]
// ---------------------------------------------------------------------------
__global__ __launch_bounds__(512) void ctrnn_proj(
    const float* __restrict__ x,    // [rows][128]
    const float* __restrict__ Win,  // [512][128]
    float* __restrict__ xp,         // [rows][512]
    int rows) {
  const int j = threadIdx.x;
  __shared__ __attribute__((aligned(16))) uint32 xb[8][64];

  uint32 w[64];
  const float2* wr = (const float2*)(Win + (size_t)j * IDIM);
#pragma unroll
  for (int p = 0; p < 64; ++p) {
    float2 f = wr[p];
    w[p] = pk2(f.x, f.y);
  }

  const int m0 = blockIdx.x * 128;
  for (int it = 0; it < 16; ++it) {
    const int mb = m0 + it * 8;
    __syncthreads();
    if (j < 256) {
      const int r = j >> 5, q = j & 31;
      const int m = mb + r;
      float4 v = make_float4(0.f, 0.f, 0.f, 0.f);
      if (m < rows) v = *(const float4*)(x + (size_t)m * IDIM + q * 4);
      xb[r][2 * q]     = pk2(v.x, v.y);
      xb[r][2 * q + 1] = pk2(v.z, v.w);
    }
    __syncthreads();
#pragma unroll
    for (int r = 0; r < 8; ++r) {
      const int m = mb + r;
      if (m < rows) {
        const uint4* xv = (const uint4*)xb[r];
        float a0 = 0.f, a1 = 0.f, a2 = 0.f, a3 = 0.f;
#pragma unroll
        for (int c = 0; c < 16; ++c) {
          uint4 hx = xv[c];
          a0 = dot2f(w[4 * c + 0], hx.x, a0);
          a1 = dot2f(w[4 * c + 1], hx.y, a1);
          a2 = dot2f(w[4 * c + 2], hx.z, a2);
          a3 = dot2f(w[4 * c + 3], hx.w, a3);
        }
        xp[(size_t)m * HDIM + j] = (a0 + a1) + (a2 + a3);
      }
    }
  }
}

// ---------------------------------------------------------------------------
// scan kernel: one block per batch sample.
// thread j: g = j&3 (K-quarter, cols [128g,128g+128)), o = j>>2.
// Computes partials for 4 outputs {o, o+128, o+256, o+384} over its quarter;
// combines across the 4 adjacent lanes via shfl_xor; finalizes output o+128g.
// Weights: per row, cols [128g,128g+96) in 192 VGPR f16-pairs; cols
// [128g+96,128g+128) in LDS wl[32][512] (conflict-free [chunk][thread]).
// h: f32 in register for own output; f16 mirror double-buffered in hq,
// quarters padded to 136 elems so broadcast lines hit disjoint banks.
// ---------------------------------------------------------------------------
__global__ __launch_bounds__(512)
__attribute__((amdgpu_waves_per_eu(2, 2)))
void ctrnn_scan(
    const float* __restrict__ xp,  // [ct][BATCH][HDIM]
    const float* __restrict__ Wh,  // [512][512]
    const float* __restrict__ h0,  // [512]
    float* __restrict__ out,       // [T][B][H] then [B][H] final hidden
    int t0, int ct) {
  const int b = blockIdx.x;
  const int j = threadIdx.x;
  const int g = j & 3;
  const int o = j >> 2;
  const int n = o + 128 * g;  // the output this thread finalizes

  __shared__ uint2 wl[32][512];                                     // 128 KB
  __shared__ __attribute__((aligned(16))) _Float16 hq[2][4][136];   // 2176 B

  // ---- load weights ----
  // regs: rows r_i = o + 128*i, cols [128g, 128g+96) -> w[i*48 + p]
  uint32 w[192];
#pragma unroll
  for (int i = 0; i < 4; ++i) {
    const float2* wr = (const float2*)(Wh + (size_t)(o + 128 * i) * HDIM + 128 * g);
#pragma unroll
    for (int p = 0; p < 48; ++p) {
      float2 f = wr[p];
      w[i * 48 + p] = pk2(f.x, f.y);
    }
  }
  // LDS: rows r_i, cols [128g+96, 128g+128) -> wl[i*8 + cp][j]
#pragma unroll
  for (int i = 0; i < 4; ++i) {
    const float4* wr4 = (const float4*)(Wh + (size_t)(o + 128 * i) * HDIM + 128 * g + 96);
#pragma unroll
    for (int cp = 0; cp < 8; ++cp) {
      float4 v = wr4[cp];
      wl[i * 8 + cp][j] = make_uint2(pk2(v.x, v.y), pk2(v.z, v.w));
    }
  }

  // ---- initial hidden ----
  float h;
  if (t0 == 0) h = h0[n];
  else h = out[((size_t)(t0 - 1) * BATCH + b) * HDIM + n];
  hq[0][g][o] = (_Float16)h;
  __syncthreads();

  float xp_cur = xp[((size_t)0 * BATCH + b) * HDIM + n];
  int cur = 0;
  for (int t = 0; t < ct; ++t) {
    const int tn = (t + 1 < ct) ? (t + 1) : t;
    const float xp_nxt = xp[((size_t)tn * BATCH + b) * HDIM + n];

    const uint4* hb = (const uint4*)&hq[cur][g][0];  // 16 x uint4 = 128 h vals
    float a0 = 0.f, a1 = 0.f, a2 = 0.f, a3 = 0.f;
    // cols [128g, 128g+96): weights in registers (12 uint4 of h, 16 dot2 each)
#pragma unroll
    for (int c = 0; c < 12; ++c) {
      uint4 hv = hb[c];
      a0 = dot2f(w[0 * 48 + 4 * c + 0], hv.x, a0);
      a0 = dot2f(w[0 * 48 + 4 * c + 1], hv.y, a0);
      a0 = dot2f(w[0 * 48 + 4 * c + 2], hv.z, a0);
      a0 = dot2f(w[0 * 48 + 4 * c + 3], hv.w, a0);
      a1 = dot2f(w[1 * 48 + 4 * c + 0], hv.x, a1);
      a1 = dot2f(w[1 * 48 + 4 * c + 1], hv.y, a1);
      a1 = dot2f(w[1 * 48 + 4 * c + 2], hv.z, a1);
      a1 = dot2f(w[1 * 48 + 4 * c + 3], hv.w, a1);
      a2 = dot2f(w[2 * 48 + 4 * c + 0], hv.x, a2);
      a2 = dot2f(w[2 * 48 + 4 * c + 1], hv.y, a2);
      a2 = dot2f(w[2 * 48 + 4 * c + 2], hv.z, a2);
      a2 = dot2f(w[2 * 48 + 4 * c + 3], hv.w, a2);
      a3 = dot2f(w[3 * 48 + 4 * c + 0], hv.x, a3);
      a3 = dot2f(w[3 * 48 + 4 * c + 1], hv.y, a3);
      a3 = dot2f(w[3 * 48 + 4 * c + 2], hv.z, a3);
      a3 = dot2f(w[3 * 48 + 4 * c + 3], hv.w, a3);
    }
    // cols [128g+96, 128g+128): weights from LDS (4 uint4 of h)
#pragma unroll
    for (int cp = 0; cp < 4; ++cp) {
      uint4 hv = hb[12 + cp];
      uint2 w0 = wl[0 * 8 + 2 * cp][j], w0b = wl[0 * 8 + 2 * cp + 1][j];
      uint2 w1 = wl[1 * 8 + 2 * cp][j], w1b = wl[1 * 8 + 2 * cp + 1][j];
      uint2 w2 = wl[2 * 8 + 2 * cp][j], w2b = wl[2 * 8 + 2 * cp + 1][j];
      uint2 w3 = wl[3 * 8 + 2 * cp][j], w3b = wl[3 * 8 + 2 * cp + 1][j];
      a0 = dot2f(w0.x, hv.x, a0); a0 = dot2f(w0.y, hv.y, a0);
      a0 = dot2f(w0b.x, hv.z, a0); a0 = dot2f(w0b.y, hv.w, a0);
      a1 = dot2f(w1.x, hv.x, a1); a1 = dot2f(w1.y, hv.y, a1);
      a1 = dot2f(w1b.x, hv.z, a1); a1 = dot2f(w1b.y, hv.w, a1);
      a2 = dot2f(w2.x, hv.x, a2); a2 = dot2f(w2.y, hv.y, a2);
      a2 = dot2f(w2b.x, hv.z, a2); a2 = dot2f(w2b.y, hv.w, a2);
      a3 = dot2f(w3.x, hv.x, a3); a3 = dot2f(w3.y, hv.y, a3);
      a3 = dot2f(w3b.x, hv.z, a3); a3 = dot2f(w3b.y, hv.w, a3);
    }

    // combine partials across the 4 K-quarters (lanes 4o..4o+3)
    a0 += __shfl_xor(a0, 1); a1 += __shfl_xor(a1, 1);
    a2 += __shfl_xor(a2, 1); a3 += __shfl_xor(a3, 1);
    a0 += __shfl_xor(a0, 2); a1 += __shfl_xor(a1, 2);
    a2 += __shfl_xor(a2, 2); a3 += __shfl_xor(a3, 2);

    // this thread finalizes output n = o + 128g -> pick partial index g
    const float zsum = (g & 1) ? ((g & 2) ? a3 : a1) : ((g & 2) ? a2 : a0);
    const float z = zsum + xp_cur;
    const float s = 1.0f / (1.0f + __expf(-z));
    h = h * (1.0f - ALPHA_F) + s * ALPHA_F;

    out[((size_t)(t0 + t) * BATCH + b) * HDIM + n] = h;
    hq[cur ^ 1][g][o] = (_Float16)h;
    __syncthreads();
    cur ^= 1;
    xp_cur = xp_nxt;
  }

  if (t0 + ct == T_STEPS) {
    out[(size_t)T_STEPS * BATCH * HDIM + (size_t)b * HDIM + n] = h;
  }
}

// ---------------------------------------------------------------------------
extern "C" void kernel_launch(void* const* d_in, const int* in_sizes, int n_in,
                              void* d_out, int out_size, void* d_ws, size_t ws_size,
                              hipStream_t stream) {
  const float* x   = (const float*)d_in[0];
  const float* Win = (const float*)d_in[1];
  const float* Wh  = (const float*)d_in[2];
  const float* h0  = (const float*)d_in[3];
  float* out = (float*)d_out;
  float* xp  = (float*)d_ws;

  const size_t step_bytes = (size_t)BATCH * HDIM * sizeof(float);  // 128 KB
  int ct_max = (int)(ws_size / step_bytes);
  if (ct_max < 1) ct_max = 1;
  if (ct_max > T_STEPS) ct_max = T_STEPS;

  for (int t0 = 0; t0 < T_STEPS; t0 += ct_max) {
    const int ct = (T_STEPS - t0 < ct_max) ? (T_STEPS - t0) : ct_max;
    const int rows = ct * BATCH;
    const int nb = (rows + 127) / 128;
    hipLaunchKernelGGL(ctrnn_proj, dim3(nb), dim3(512), 0, stream,
                       x + (size_t)t0 * BATCH * IDIM, Win, xp, rows);
    hipLaunchKernelGGL(ctrnn_scan, dim3(BATCH), dim3(512), 0, stream,
                       xp, Wh, h0, out, t0, ct);
  }
}

// Round 6
// 1290.484 us; speedup vs baseline: 1.5165x; 1.3967x over previous
//
#include <hip/hip_runtime.h>

#define T_STEPS 1024
#define BATCH   64
#define IDIM    128
#define HDIM    512
#define ALPHA_F 0.02f

typedef _Float16 half2_t __attribute__((ext_vector_type(2)));
typedef unsigned int uint32;

// packed f16 dot2 with f32 accumulate: acc += a.x*b.x + a.y*b.y
__device__ __forceinline__ float dot2f(uint32 w, uint32 h, float acc) {
#if __has_builtin(__builtin_amdgcn_fdot2)
  return __builtin_amdgcn_fdot2(__builtin_bit_cast(half2_t, w),
                                __builtin_bit_cast(half2_t, h), acc, false);
#else
  half2_t a = __builtin_bit_cast(half2_t, w);
  half2_t b = __builtin_bit_cast(half2_t, h);
  return acc + (float)a.x * (float)b.x + (float)a.y * (float)b.y;
#endif
}

__device__ __forceinline__ uint32 pk2(float a, float b) {
  auto p = __builtin_amdgcn_cvt_pkrtz(a, b);
  return __builtin_bit_cast(uint32, p);
}

// i8x4 dot product with i32 accumulate
__device__ __forceinline__ int dot4i8(uint32 a, uint32 b, int c) {
#if __has_builtin(__builtin_amdgcn_sdot4)
  return __builtin_amdgcn_sdot4((int)a, (int)b, c, false);
#else
  int s = c;
  s += (int)(signed char)(a)        * (int)(signed char)(b);
  s += (int)(signed char)(a >> 8)   * (int)(signed char)(b >> 8);
  s += (int)(signed char)(a >> 16)  * (int)(signed char)(b >> 16);
  s += (int)(signed char)(a >> 24)  * (int)(signed char)(b >> 24);
  return s;
#endif
}

// quantize 4 floats by inv, pack to i8x4 dword
__device__ __forceinline__ uint32 pkq(float v0, float v1, float v2, float v3, float inv) {
  int i0 = __float2int_rn(v0 * inv), i1 = __float2int_rn(v1 * inv);
  int i2 = __float2int_rn(v2 * inv), i3 = __float2int_rn(v3 * inv);
  return (uint32)(i0 & 255) | ((uint32)(i1 & 255) << 8) |
         ((uint32)(i2 & 255) << 16) | ((uint32)(i3 & 255) << 24);
}

// ---------------------------------------------------------------------------
// x_proj kernel: xp[m][j] = sum_i x[m][i] * Win[j][i]  (f16 dot2)
// ---------------------------------------------------------------------------
__global__ __launch_bounds__(512) void ctrnn_proj(
    const float* __restrict__ x,    // [rows][128]
    const float* __restrict__ Win,  // [512][128]
    float* __restrict__ xp,         // [rows][512]
    int rows) {
  const int j = threadIdx.x;
  __shared__ __attribute__((aligned(16))) uint32 xb[8][64];

  uint32 w[64];
  const float2* wr = (const float2*)(Win + (size_t)j * IDIM);
#pragma unroll
  for (int p = 0; p < 64; ++p) {
    float2 f = wr[p];
    w[p] = pk2(f.x, f.y);
  }

  const int m0 = blockIdx.x * 128;
  for (int it = 0; it < 16; ++it) {
    const int mb = m0 + it * 8;
    __syncthreads();
    if (j < 256) {
      const int r = j >> 5, q = j & 31;
      const int m = mb + r;
      float4 v = make_float4(0.f, 0.f, 0.f, 0.f);
      if (m < rows) v = *(const float4*)(x + (size_t)m * IDIM + q * 4);
      xb[r][2 * q]     = pk2(v.x, v.y);
      xb[r][2 * q + 1] = pk2(v.z, v.w);
    }
    __syncthreads();
#pragma unroll
    for (int r = 0; r < 8; ++r) {
      const int m = mb + r;
      if (m < rows) {
        const uint4* xv = (const uint4*)xb[r];
        float a0 = 0.f, a1 = 0.f, a2 = 0.f, a3 = 0.f;
#pragma unroll
        for (int c = 0; c < 16; ++c) {
          uint4 hx = xv[c];
          a0 = dot2f(w[4 * c + 0], hx.x, a0);
          a1 = dot2f(w[4 * c + 1], hx.y, a1);
          a2 = dot2f(w[4 * c + 2], hx.z, a2);
          a3 = dot2f(w[4 * c + 3], hx.w, a3);
        }
        xp[(size_t)m * HDIM + j] = (a0 + a1) + (a2 + a3);
      }
    }
  }
}

// ---------------------------------------------------------------------------
// scan kernel: 1 block/batch, 1024 threads.
// thread j: g = j&7 (K-eighth, cols [64g,64g+64)), o = j>>3 (rows 4o..4o+3),
// r = g&3 (the row 4o+r this lane finalizes).
// W_h quantized to i8 with per-row scale; row slice = 64 dwords in VGPRs.
// i32 partials -> exact; combined across 8 slices via shfl_xor x3; per-row
// scale applied after reduce. h state f32 in register (lane-distributed);
// i8 mirror double-buffered in hq[2][8][80] (80B slice stride -> each
// ds_read_b128 hits 8 disjoint 4-bank groups, conflict-free).
// ---------------------------------------------------------------------------
__global__ __launch_bounds__(1024) void ctrnn_scan(
    const float* __restrict__ xp,  // [ct][BATCH][HDIM]
    const float* __restrict__ Wh,  // [512][512]
    const float* __restrict__ h0,  // [512]
    float* __restrict__ out,       // [T][B][H] then [B][H] final hidden
    int t0, int ct) {
  const int b = blockIdx.x;
  const int j = threadIdx.x;
  const int g = j & 7;
  const int o = j >> 3;
  const int r = g & 3;
  const int n = 4 * o + r;  // the output row this lane finalizes

  __shared__ __attribute__((aligned(16))) unsigned char hq[2][8][80];

  // ---- pass 1: per-row absmax (full row via 3-round butterfly max) ----
  float rmax0, rmax1, rmax2, rmax3;
#pragma unroll
  for (int i = 0; i < 4; ++i) {
    const float4* wr = (const float4*)(Wh + (size_t)(4 * o + i) * HDIM + 64 * g);
    float m = 0.f;
#pragma unroll
    for (int c = 0; c < 16; ++c) {
      float4 v = wr[c];
      m = fmaxf(m, fmaxf(fmaxf(fabsf(v.x), fabsf(v.y)), fmaxf(fabsf(v.z), fabsf(v.w))));
    }
    m = fmaxf(m, __shfl_xor(m, 1));
    m = fmaxf(m, __shfl_xor(m, 2));
    m = fmaxf(m, __shfl_xor(m, 4));
    if (i == 0) rmax0 = m; else if (i == 1) rmax1 = m;
    else if (i == 2) rmax2 = m; else rmax3 = m;
  }

  // ---- pass 2: quantize row slices into 64 register dwords ----
  uint32 w[64];
#pragma unroll
  for (int i = 0; i < 4; ++i) {
    const float rm = (i == 0) ? rmax0 : (i == 1) ? rmax1 : (i == 2) ? rmax2 : rmax3;
    const float inv = (rm > 0.f) ? 127.f / rm : 0.f;
    const float4* wr = (const float4*)(Wh + (size_t)(4 * o + i) * HDIM + 64 * g);
#pragma unroll
    for (int c = 0; c < 16; ++c) {
      float4 v = wr[c];
      w[i * 16 + c] = pkq(v.x, v.y, v.z, v.w, inv);
    }
  }
  const float rm_own = (r & 1) ? ((r & 2) ? rmax3 : rmax1) : ((r & 2) ? rmax2 : rmax0);
  const float fscale = rm_own * (1.f / (127.f * 127.f));

  // ---- initial hidden (f32 state, lane-distributed; i8 mirror in LDS) ----
  float h;
  if (t0 == 0) h = h0[n];
  else h = out[((size_t)(t0 - 1) * BATCH + b) * HDIM + n];
  {
    uint32 bb = (uint32)(__float2int_rn(h * 127.f) & 255);
    uint32 c1 = bb | (__shfl_xor((int)bb, 1) << 8);
    uint32 dw = c1 | (__shfl_xor((int)c1, 2) << 16);
    if (g == 0) *((uint32*)&hq[0][o >> 4][(4 * o) & 63]) = dw;
  }
  __syncthreads();

  const size_t xoff = (size_t)b * HDIM + n;
  float xp_cur = xp[xoff];  // t = 0
  int cur = 0;
  for (int t = 0; t < ct; ++t) {
    const int tn = (t + 1 < ct) ? (t + 1) : t;
    const float xp_nxt = xp[(size_t)tn * BATCH * HDIM + xoff];

    const uint4* hb = (const uint4*)(&hq[cur][g][0]);
    int a0 = 0, a1 = 0, a2 = 0, a3 = 0;
#pragma unroll
    for (int c = 0; c < 4; ++c) {
      uint4 hv = hb[c];
      a0 = dot4i8(w[0 * 16 + 4 * c + 0], hv.x, a0);
      a0 = dot4i8(w[0 * 16 + 4 * c + 1], hv.y, a0);
      a0 = dot4i8(w[0 * 16 + 4 * c + 2], hv.z, a0);
      a0 = dot4i8(w[0 * 16 + 4 * c + 3], hv.w, a0);
      a1 = dot4i8(w[1 * 16 + 4 * c + 0], hv.x, a1);
      a1 = dot4i8(w[1 * 16 + 4 * c + 1], hv.y, a1);
      a1 = dot4i8(w[1 * 16 + 4 * c + 2], hv.z, a1);
      a1 = dot4i8(w[1 * 16 + 4 * c + 3], hv.w, a1);
      a2 = dot4i8(w[2 * 16 + 4 * c + 0], hv.x, a2);
      a2 = dot4i8(w[2 * 16 + 4 * c + 1], hv.y, a2);
      a2 = dot4i8(w[2 * 16 + 4 * c + 2], hv.z, a2);
      a2 = dot4i8(w[2 * 16 + 4 * c + 3], hv.w, a2);
      a3 = dot4i8(w[3 * 16 + 4 * c + 0], hv.x, a3);
      a3 = dot4i8(w[3 * 16 + 4 * c + 1], hv.y, a3);
      a3 = dot4i8(w[3 * 16 + 4 * c + 2], hv.z, a3);
      a3 = dot4i8(w[3 * 16 + 4 * c + 3], hv.w, a3);
    }
    // combine the 8 K-slices (exact i32 adds)
    a0 += __shfl_xor(a0, 1); a1 += __shfl_xor(a1, 1);
    a2 += __shfl_xor(a2, 1); a3 += __shfl_xor(a3, 1);
    a0 += __shfl_xor(a0, 2); a1 += __shfl_xor(a1, 2);
    a2 += __shfl_xor(a2, 2); a3 += __shfl_xor(a3, 2);
    a0 += __shfl_xor(a0, 4); a1 += __shfl_xor(a1, 4);
    a2 += __shfl_xor(a2, 4); a3 += __shfl_xor(a3, 4);

    const int av = (r & 1) ? ((r & 2) ? a3 : a1) : ((r & 2) ? a2 : a0);
    const float z = (float)av * fscale + xp_cur;
    const float s = 1.0f / (1.0f + __expf(-z));
    h = h * (1.0f - ALPHA_F) + s * ALPHA_F;

    if (g < 4) out[((size_t)(t0 + t) * BATCH + b) * HDIM + n] = h;

    uint32 bb = (uint32)(__float2int_rn(h * 127.f) & 255);
    uint32 c1 = bb | (__shfl_xor((int)bb, 1) << 8);
    uint32 dw = c1 | (__shfl_xor((int)c1, 2) << 16);
    if (g == 0) *((uint32*)&hq[cur ^ 1][o >> 4][(4 * o) & 63]) = dw;
    __syncthreads();
    cur ^= 1;
    xp_cur = xp_nxt;
  }

  if (t0 + ct == T_STEPS && g < 4) {
    out[(size_t)T_STEPS * BATCH * HDIM + (size_t)b * HDIM + n] = h;
  }
}

// ---------------------------------------------------------------------------
extern "C" void kernel_launch(void* const* d_in, const int* in_sizes, int n_in,
                              void* d_out, int out_size, void* d_ws, size_t ws_size,
                              hipStream_t stream) {
  const float* x   = (const float*)d_in[0];
  const float* Win = (const float*)d_in[1];
  const float* Wh  = (const float*)d_in[2];
  const float* h0  = (const float*)d_in[3];
  float* out = (float*)d_out;
  float* xp  = (float*)d_ws;

  const size_t step_bytes = (size_t)BATCH * HDIM * sizeof(float);  // 128 KB
  int ct_max = (int)(ws_size / step_bytes);
  if (ct_max < 1) ct_max = 1;
  if (ct_max > T_STEPS) ct_max = T_STEPS;

  for (int t0 = 0; t0 < T_STEPS; t0 += ct_max) {
    const int ct = (T_STEPS - t0 < ct_max) ? (T_STEPS - t0) : ct_max;
    const int rows = ct * BATCH;
    const int nb = (rows + 127) / 128;
    hipLaunchKernelGGL(ctrnn_proj, dim3(nb), dim3(512), 0, stream,
                       x + (size_t)t0 * BATCH * IDIM, Win, xp, rows);
    hipLaunchKernelGGL(ctrnn_scan, dim3(BATCH), dim3(1024), 0, stream,
                       xp, Wh, h0, out, t0, ct);
  }
}

// Round 9
// 1258.927 us; speedup vs baseline: 1.5545x; 1.0251x over previous
//
// CTRNN MI355X — R9 submission (identical experiment to R7/R8; resubmitted past infra flake)
#include <hip/hip_runtime.h>

#define T_STEPS 1024
#define BATCH   64
#define IDIM    128
#define HDIM    512
#define ALPHA_F 0.02f

typedef _Float16 half2_t __attribute__((ext_vector_type(2)));
typedef unsigned int uint32;

// packed f16 dot2 with f32 accumulate: acc += a.x*b.x + a.y*b.y
__device__ __forceinline__ float dot2f(uint32 w, uint32 h, float acc) {
#if __has_builtin(__builtin_amdgcn_fdot2)
  return __builtin_amdgcn_fdot2(__builtin_bit_cast(half2_t, w),
                                __builtin_bit_cast(half2_t, h), acc, false);
#else
  half2_t a = __builtin_bit_cast(half2_t, w);
  half2_t b = __builtin_bit_cast(half2_t, h);
  return acc + (float)a.x * (float)b.x + (float)a.y * (float)b.y;
#endif
}

__device__ __forceinline__ uint32 pk2(float a, float b) {
  auto p = __builtin_amdgcn_cvt_pkrtz(a, b);
  return __builtin_bit_cast(uint32, p);
}

// i8x4 dot product with i32 accumulate
__device__ __forceinline__ int dot4i8(uint32 a, uint32 b, int c) {
#if __has_builtin(__builtin_amdgcn_sdot4)
  return __builtin_amdgcn_sdot4((int)a, (int)b, c, false);
#else
  int s = c;
  s += (int)(signed char)(a)        * (int)(signed char)(b);
  s += (int)(signed char)(a >> 8)   * (int)(signed char)(b >> 8);
  s += (int)(signed char)(a >> 16)  * (int)(signed char)(b >> 16);
  s += (int)(signed char)(a >> 24)  * (int)(signed char)(b >> 24);
  return s;
#endif
}

// quantize 4 floats by inv, pack to i8x4 dword
__device__ __forceinline__ uint32 pkq(float v0, float v1, float v2, float v3, float inv) {
  int i0 = __float2int_rn(v0 * inv), i1 = __float2int_rn(v1 * inv);
  int i2 = __float2int_rn(v2 * inv), i3 = __float2int_rn(v3 * inv);
  return (uint32)(i0 & 255) | ((uint32)(i1 & 255) << 8) |
         ((uint32)(i2 & 255) << 16) | ((uint32)(i3 & 255) << 24);
}

// ---------------------------------------------------------------------------
// x_proj kernel: xp[m][j] = sum_i x[m][i] * Win[j][i]  (f16 dot2)
// ---------------------------------------------------------------------------
__global__ __launch_bounds__(512) void ctrnn_proj(
    const float* __restrict__ x,    // [rows][128]
    const float* __restrict__ Win,  // [512][128]
    float* __restrict__ xp,         // [rows][512]
    int rows) {
  const int j = threadIdx.x;
  __shared__ __attribute__((aligned(16))) uint32 xb[8][64];

  uint32 w[64];
  const float2* wr = (const float2*)(Win + (size_t)j * IDIM);
#pragma unroll
  for (int p = 0; p < 64; ++p) {
    float2 f = wr[p];
    w[p] = pk2(f.x, f.y);
  }

  const int m0 = blockIdx.x * 128;
  for (int it = 0; it < 16; ++it) {
    const int mb = m0 + it * 8;
    __syncthreads();
    if (j < 256) {
      const int r = j >> 5, q = j & 31;
      const int m = mb + r;
      float4 v = make_float4(0.f, 0.f, 0.f, 0.f);
      if (m < rows) v = *(const float4*)(x + (size_t)m * IDIM + q * 4);
      xb[r][2 * q]     = pk2(v.x, v.y);
      xb[r][2 * q + 1] = pk2(v.z, v.w);
    }
    __syncthreads();
#pragma unroll
    for (int r = 0; r < 8; ++r) {
      const int m = mb + r;
      if (m < rows) {
        const uint4* xv = (const uint4*)xb[r];
        float a0 = 0.f, a1 = 0.f, a2 = 0.f, a3 = 0.f;
#pragma unroll
        for (int c = 0; c < 16; ++c) {
          uint4 hx = xv[c];
          a0 = dot2f(w[4 * c + 0], hx.x, a0);
          a1 = dot2f(w[4 * c + 1], hx.y, a1);
          a2 = dot2f(w[4 * c + 2], hx.z, a2);
          a3 = dot2f(w[4 * c + 3], hx.w, a3);
        }
        xp[(size_t)m * HDIM + j] = (a0 + a1) + (a2 + a3);
      }
    }
  }
}

// ---------------------------------------------------------------------------
// scan kernel: 1 block/batch, 1024 threads, EXACTLY 4 waves/EU (one block/CU).
// amdgpu_waves_per_eu(4,4) unlocks the full 128-VGPR budget so w[64] stays
// arch-VGPR-resident (R6 post-mortem: default heuristic targeted 8 waves/EU,
// allocated 64 VGPRs, spilled weights to AGPR/scratch -> ~2x inst inflation).
// thread j: g = j&7 (K-eighth, cols [64g,64g+64)), o = j>>3 (rows 4o..4o+3),
// r = g&3 (the row 4o+r this lane finalizes).
// ---------------------------------------------------------------------------
__global__ __launch_bounds__(1024)
__attribute__((amdgpu_waves_per_eu(4, 4)))
void ctrnn_scan(
    const float* __restrict__ xp,  // [ct][BATCH][HDIM]
    const float* __restrict__ Wh,  // [512][512]
    const float* __restrict__ h0,  // [512]
    float* __restrict__ out,       // [T][B][H] then [B][H] final hidden
    int t0, int ct) {
  const int b = blockIdx.x;
  const int j = threadIdx.x;
  const int g = j & 7;
  const int o = j >> 3;
  const int r = g & 3;
  const int n = 4 * o + r;  // the output row this lane finalizes

  __shared__ __attribute__((aligned(16))) unsigned char hq[2][8][80];

  // ---- pass 1: per-row absmax (full row via 3-round butterfly max) ----
  float rmax0, rmax1, rmax2, rmax3;
#pragma unroll
  for (int i = 0; i < 4; ++i) {
    const float4* wr = (const float4*)(Wh + (size_t)(4 * o + i) * HDIM + 64 * g);
    float m = 0.f;
#pragma unroll
    for (int c = 0; c < 16; ++c) {
      float4 v = wr[c];
      m = fmaxf(m, fmaxf(fmaxf(fabsf(v.x), fabsf(v.y)), fmaxf(fabsf(v.z), fabsf(v.w))));
    }
    m = fmaxf(m, __shfl_xor(m, 1));
    m = fmaxf(m, __shfl_xor(m, 2));
    m = fmaxf(m, __shfl_xor(m, 4));
    if (i == 0) rmax0 = m; else if (i == 1) rmax1 = m;
    else if (i == 2) rmax2 = m; else rmax3 = m;
  }

  // ---- pass 2: quantize row slices into 64 register dwords ----
  uint32 w[64];
#pragma unroll
  for (int i = 0; i < 4; ++i) {
    const float rm = (i == 0) ? rmax0 : (i == 1) ? rmax1 : (i == 2) ? rmax2 : rmax3;
    const float inv = (rm > 0.f) ? 127.f / rm : 0.f;
    const float4* wr = (const float4*)(Wh + (size_t)(4 * o + i) * HDIM + 64 * g);
#pragma unroll
    for (int c = 0; c < 16; ++c) {
      float4 v = wr[c];
      w[i * 16 + c] = pkq(v.x, v.y, v.z, v.w, inv);
    }
  }
  const float rm_own = (r & 1) ? ((r & 2) ? rmax3 : rmax1) : ((r & 2) ? rmax2 : rmax0);
  const float fscale = rm_own * (1.f / (127.f * 127.f));

  // ---- initial hidden (f32 state, lane-distributed; i8 mirror in LDS) ----
  float h;
  if (t0 == 0) h = h0[n];
  else h = out[((size_t)(t0 - 1) * BATCH + b) * HDIM + n];
  {
    uint32 bb = (uint32)(__float2int_rn(h * 127.f) & 255);
    uint32 c1 = bb | (__shfl_xor((int)bb, 1) << 8);
    uint32 dw = c1 | (__shfl_xor((int)c1, 2) << 16);
    if (g == 0) *((uint32*)&hq[0][o >> 4][(4 * o) & 63]) = dw;
  }
  __syncthreads();

  // running pointers (no per-step 64-bit mults)
  const float* xpp = xp + (size_t)b * HDIM + n;                       // current t
  float* outp = out + ((size_t)t0 * BATCH + b) * HDIM + n;            // current t
  const size_t BH = (size_t)BATCH * HDIM;

  float xp_cur = xpp[0];
  int cur = 0;
  for (int t = 0; t < ct; ++t) {
    const float xp_nxt = xpp[(t + 1 < ct) ? BH : 0];

    const uint4* hb = (const uint4*)(&hq[cur][g][0]);
    int a0 = 0, a1 = 0, a2 = 0, a3 = 0;
#pragma unroll
    for (int c = 0; c < 4; ++c) {
      uint4 hv = hb[c];
      a0 = dot4i8(w[0 * 16 + 4 * c + 0], hv.x, a0);
      a0 = dot4i8(w[0 * 16 + 4 * c + 1], hv.y, a0);
      a0 = dot4i8(w[0 * 16 + 4 * c + 2], hv.z, a0);
      a0 = dot4i8(w[0 * 16 + 4 * c + 3], hv.w, a0);
      a1 = dot4i8(w[1 * 16 + 4 * c + 0], hv.x, a1);
      a1 = dot4i8(w[1 * 16 + 4 * c + 1], hv.y, a1);
      a1 = dot4i8(w[1 * 16 + 4 * c + 2], hv.z, a1);
      a1 = dot4i8(w[1 * 16 + 4 * c + 3], hv.w, a1);
      a2 = dot4i8(w[2 * 16 + 4 * c + 0], hv.x, a2);
      a2 = dot4i8(w[2 * 16 + 4 * c + 1], hv.y, a2);
      a2 = dot4i8(w[2 * 16 + 4 * c + 2], hv.z, a2);
      a2 = dot4i8(w[2 * 16 + 4 * c + 3], hv.w, a2);
      a3 = dot4i8(w[3 * 16 + 4 * c + 0], hv.x, a3);
      a3 = dot4i8(w[3 * 16 + 4 * c + 1], hv.y, a3);
      a3 = dot4i8(w[3 * 16 + 4 * c + 2], hv.z, a3);
      a3 = dot4i8(w[3 * 16 + 4 * c + 3], hv.w, a3);
    }
    // combine the 8 K-slices (exact i32 adds)
    a0 += __shfl_xor(a0, 1); a1 += __shfl_xor(a1, 1);
    a2 += __shfl_xor(a2, 1); a3 += __shfl_xor(a3, 1);
    a0 += __shfl_xor(a0, 2); a1 += __shfl_xor(a1, 2);
    a2 += __shfl_xor(a2, 2); a3 += __shfl_xor(a3, 2);
    a0 += __shfl_xor(a0, 4); a1 += __shfl_xor(a1, 4);
    a2 += __shfl_xor(a2, 4); a3 += __shfl_xor(a3, 4);

    const int av = (r & 1) ? ((r & 2) ? a3 : a1) : ((r & 2) ? a2 : a0);
    const float z = (float)av * fscale + xp_cur;
    const float s = 1.0f / (1.0f + __expf(-z));
    h = h * (1.0f - ALPHA_F) + s * ALPHA_F;

    if (g < 4) *outp = h;

    uint32 bb = (uint32)(__float2int_rn(h * 127.f) & 255);
    uint32 c1 = bb | (__shfl_xor((int)bb, 1) << 8);
    uint32 dw = c1 | (__shfl_xor((int)c1, 2) << 16);
    if (g == 0) *((uint32*)&hq[cur ^ 1][o >> 4][(4 * o) & 63]) = dw;
    __syncthreads();
    cur ^= 1;
    xp_cur = xp_nxt;
    xpp += BH;
    outp += BH;
  }

  if (t0 + ct == T_STEPS && g < 4) {
    out[(size_t)T_STEPS * BATCH * HDIM + (size_t)b * HDIM + n] = h;
  }
}

// ---------------------------------------------------------------------------
extern "C" void kernel_launch(void* const* d_in, const int* in_sizes, int n_in,
                              void* d_out, int out_size, void* d_ws, size_t ws_size,
                              hipStream_t stream) {
  const float* x   = (const float*)d_in[0];
  const float* Win = (const float*)d_in[1];
  const float* Wh  = (const float*)d_in[2];
  const float* h0  = (const float*)d_in[3];
  float* out = (float*)d_out;
  float* xp  = (float*)d_ws;

  const size_t step_bytes = (size_t)BATCH * HDIM * sizeof(float);  // 128 KB
  int ct_max = (int)(ws_size / step_bytes);
  if (ct_max < 1) ct_max = 1;
  if (ct_max > T_STEPS) ct_max = T_STEPS;

  for (int t0 = 0; t0 < T_STEPS; t0 += ct_max) {
    const int ct = (T_STEPS - t0 < ct_max) ? (T_STEPS - t0) : ct_max;
    const int rows = ct * BATCH;
    const int nb = (rows + 127) / 128;
    hipLaunchKernelGGL(ctrnn_proj, dim3(nb), dim3(512), 0, stream,
                       x + (size_t)t0 * BATCH * IDIM, Win, xp, rows);
    hipLaunchKernelGGL(ctrnn_scan, dim3(BATCH), dim3(1024), 0, stream,
                       xp, Wh, h0, out, t0, ct);
  }
}

// Round 10
// 1103.066 us; speedup vs baseline: 1.7742x; 1.1413x over previous
//
// CTRNN MI355X — R10: 512-thread scan, 2 waves/EU -> 128 arch VGPRs, K-quarter decomposition
#include <hip/hip_runtime.h>

#define T_STEPS 1024
#define BATCH   64
#define IDIM    128
#define HDIM    512
#define ALPHA_F 0.02f

typedef _Float16 half2_t __attribute__((ext_vector_type(2)));
typedef unsigned int uint32;

// packed f16 dot2 with f32 accumulate
__device__ __forceinline__ float dot2f(uint32 w, uint32 h, float acc) {
#if __has_builtin(__builtin_amdgcn_fdot2)
  return __builtin_amdgcn_fdot2(__builtin_bit_cast(half2_t, w),
                                __builtin_bit_cast(half2_t, h), acc, false);
#else
  half2_t a = __builtin_bit_cast(half2_t, w);
  half2_t b = __builtin_bit_cast(half2_t, h);
  return acc + (float)a.x * (float)b.x + (float)a.y * (float)b.y;
#endif
}

__device__ __forceinline__ uint32 pk2(float a, float b) {
  auto p = __builtin_amdgcn_cvt_pkrtz(a, b);
  return __builtin_bit_cast(uint32, p);
}

// i8x4 dot product with i32 accumulate
__device__ __forceinline__ int dot4i8(uint32 a, uint32 b, int c) {
#if __has_builtin(__builtin_amdgcn_sdot4)
  return __builtin_amdgcn_sdot4((int)a, (int)b, c, false);
#else
  int s = c;
  s += (int)(signed char)(a)        * (int)(signed char)(b);
  s += (int)(signed char)(a >> 8)   * (int)(signed char)(b >> 8);
  s += (int)(signed char)(a >> 16)  * (int)(signed char)(b >> 16);
  s += (int)(signed char)(a >> 24)  * (int)(signed char)(b >> 24);
  return s;
#endif
}

// quantize 4 floats by inv, pack to i8x4 dword
__device__ __forceinline__ uint32 pkq(float v0, float v1, float v2, float v3, float inv) {
  int i0 = __float2int_rn(v0 * inv), i1 = __float2int_rn(v1 * inv);
  int i2 = __float2int_rn(v2 * inv), i3 = __float2int_rn(v3 * inv);
  return (uint32)(i0 & 255) | ((uint32)(i1 & 255) << 8) |
         ((uint32)(i2 & 255) << 16) | ((uint32)(i3 & 255) << 24);
}

// ---------------------------------------------------------------------------
// x_proj kernel: xp[m][j] = sum_i x[m][i] * Win[j][i]  (f16 dot2)
// ---------------------------------------------------------------------------
__global__ __launch_bounds__(512) void ctrnn_proj(
    const float* __restrict__ x,    // [rows][128]
    const float* __restrict__ Win,  // [512][128]
    float* __restrict__ xp,         // [rows][512]
    int rows) {
  const int j = threadIdx.x;
  __shared__ __attribute__((aligned(16))) uint32 xb[8][64];

  uint32 w[64];
  const float2* wr = (const float2*)(Win + (size_t)j * IDIM);
#pragma unroll
  for (int p = 0; p < 64; ++p) {
    float2 f = wr[p];
    w[p] = pk2(f.x, f.y);
  }

  const int m0 = blockIdx.x * 128;
  for (int it = 0; it < 16; ++it) {
    const int mb = m0 + it * 8;
    __syncthreads();
    if (j < 256) {
      const int r = j >> 5, q = j & 31;
      const int m = mb + r;
      float4 v = make_float4(0.f, 0.f, 0.f, 0.f);
      if (m < rows) v = *(const float4*)(x + (size_t)m * IDIM + q * 4);
      xb[r][2 * q]     = pk2(v.x, v.y);
      xb[r][2 * q + 1] = pk2(v.z, v.w);
    }
    __syncthreads();
#pragma unroll
    for (int r = 0; r < 8; ++r) {
      const int m = mb + r;
      if (m < rows) {
        const uint4* xv = (const uint4*)xb[r];
        float a0 = 0.f, a1 = 0.f, a2 = 0.f, a3 = 0.f;
#pragma unroll
        for (int c = 0; c < 16; ++c) {
          uint4 hx = xv[c];
          a0 = dot2f(w[4 * c + 0], hx.x, a0);
          a1 = dot2f(w[4 * c + 1], hx.y, a1);
          a2 = dot2f(w[4 * c + 2], hx.z, a2);
          a3 = dot2f(w[4 * c + 3], hx.w, a3);
        }
        xp[(size_t)m * HDIM + j] = (a0 + a1) + (a2 + a3);
      }
    }
  }
}

// ---------------------------------------------------------------------------
// scan kernel: 1 block/batch, 512 threads (8 waves = 2/SIMD -> 128 arch VGPRs,
// the grant observed in R2/R3; minimizes AGPR-parked fraction of w[128]).
// thread j: g = j&3 (K-quarter, cols [128g,128g+128) = 32 i8 dwords),
// o = j>>2 (rows 4o..4o+3). Lane finalizes row n = 4o+g == j (coalesced IO).
// i32 partials combined across the 4 quarter-lanes via 2 shfl_xor rounds.
// h mirror: i8, quarters at 144-byte stride (disjoint bank quads, broadcast
// within 16-lane quarter groups, conflict-free b128 reads).
// ---------------------------------------------------------------------------
__global__ __launch_bounds__(512)
__attribute__((amdgpu_waves_per_eu(2, 2)))
void ctrnn_scan(
    const float* __restrict__ xp,  // [ct][BATCH][HDIM]
    const float* __restrict__ Wh,  // [512][512]
    const float* __restrict__ h0,  // [512]
    float* __restrict__ out,       // [T][B][H] then [B][H] final hidden
    int t0, int ct) {
  const int b = blockIdx.x;
  const int j = threadIdx.x;   // == output row n
  const int g = j & 3;
  const int o = j >> 2;

  __shared__ __attribute__((aligned(16))) unsigned char hq[2][576];

  // ---- pass 1: per-row absmax over full rows 4o..4o+3 (partial + 2-round butterfly) ----
  float r0, r1, r2, r3;
#pragma unroll
  for (int i = 0; i < 4; ++i) {
    const float4* wr = (const float4*)(Wh + (size_t)(4 * o + i) * HDIM + 128 * g);
    float m = 0.f;
#pragma unroll
    for (int c = 0; c < 32; ++c) {
      float4 v = wr[c];
      m = fmaxf(m, fmaxf(fmaxf(fabsf(v.x), fabsf(v.y)), fmaxf(fabsf(v.z), fabsf(v.w))));
    }
    m = fmaxf(m, __shfl_xor(m, 1));
    m = fmaxf(m, __shfl_xor(m, 2));
    if (i == 0) r0 = m; else if (i == 1) r1 = m; else if (i == 2) r2 = m; else r3 = m;
  }

  // ---- pass 2: quantize 4 rows x 32 dwords into w[128] ----
  uint32 w[128];
#pragma unroll
  for (int i = 0; i < 4; ++i) {
    const float rm = (i == 0) ? r0 : (i == 1) ? r1 : (i == 2) ? r2 : r3;
    const float inv = (rm > 0.f) ? 127.f / rm : 0.f;
    const float4* wr = (const float4*)(Wh + (size_t)(4 * o + i) * HDIM + 128 * g);
#pragma unroll
    for (int c = 0; c < 32; ++c) {
      float4 v = wr[c];
      w[i * 32 + c] = pkq(v.x, v.y, v.z, v.w, inv);
    }
  }
  const float rm_own = (g & 1) ? ((g & 2) ? r3 : r1) : ((g & 2) ? r2 : r0);
  const float fscale = rm_own * (1.f / (127.f * 127.f));

  // ---- initial hidden: h (f32) in register, i8 mirror packed into hq[0] ----
  float h;
  if (t0 == 0) h = h0[j];
  else h = out[((size_t)(t0 - 1) * BATCH + b) * HDIM + j];
  {
    uint32 bb = (uint32)(__float2int_rn(h * 127.f) & 255);
    uint32 c1 = bb | ((uint32)__shfl_xor((int)bb, 1) << 8);
    uint32 dw = c1 | ((uint32)__shfl_xor((int)c1, 2) << 16);
    if (g == 0) *((uint32*)&hq[0][144 * (o >> 5) + ((4 * o) & 127)]) = dw;
  }
  __syncthreads();

  const float* xpp = xp + (size_t)b * HDIM + j;
  float* outp = out + ((size_t)t0 * BATCH + b) * HDIM + j;
  const size_t BH = (size_t)BATCH * HDIM;

  float xp_cur = xpp[0];
  int cur = 0;
  for (int t = 0; t < ct; ++t) {
    const float xp_nxt = xpp[(t + 1 < ct) ? BH : 0];

    const uint4* hb = (const uint4*)(&hq[cur][144 * g]);  // 8 x b128 = 128 h bytes
    int a0 = 0, a1 = 0, a2 = 0, a3 = 0;
#pragma unroll
    for (int c2 = 0; c2 < 8; ++c2) {
      uint4 hv = hb[c2];
      a0 = dot4i8(w[0 * 32 + 4 * c2 + 0], hv.x, a0);
      a0 = dot4i8(w[0 * 32 + 4 * c2 + 1], hv.y, a0);
      a0 = dot4i8(w[0 * 32 + 4 * c2 + 2], hv.z, a0);
      a0 = dot4i8(w[0 * 32 + 4 * c2 + 3], hv.w, a0);
      a1 = dot4i8(w[1 * 32 + 4 * c2 + 0], hv.x, a1);
      a1 = dot4i8(w[1 * 32 + 4 * c2 + 1], hv.y, a1);
      a1 = dot4i8(w[1 * 32 + 4 * c2 + 2], hv.z, a1);
      a1 = dot4i8(w[1 * 32 + 4 * c2 + 3], hv.w, a1);
      a2 = dot4i8(w[2 * 32 + 4 * c2 + 0], hv.x, a2);
      a2 = dot4i8(w[2 * 32 + 4 * c2 + 1], hv.y, a2);
      a2 = dot4i8(w[2 * 32 + 4 * c2 + 2], hv.z, a2);
      a2 = dot4i8(w[2 * 32 + 4 * c2 + 3], hv.w, a2);
      a3 = dot4i8(w[3 * 32 + 4 * c2 + 0], hv.x, a3);
      a3 = dot4i8(w[3 * 32 + 4 * c2 + 1], hv.y, a3);
      a3 = dot4i8(w[3 * 32 + 4 * c2 + 2], hv.z, a3);
      a3 = dot4i8(w[3 * 32 + 4 * c2 + 3], hv.w, a3);
    }
    // combine the 4 K-quarters (exact i32 adds) across lanes 4o..4o+3
    a0 += __shfl_xor(a0, 1); a1 += __shfl_xor(a1, 1);
    a2 += __shfl_xor(a2, 1); a3 += __shfl_xor(a3, 1);
    a0 += __shfl_xor(a0, 2); a1 += __shfl_xor(a1, 2);
    a2 += __shfl_xor(a2, 2); a3 += __shfl_xor(a3, 2);

    const int av = (g & 1) ? ((g & 2) ? a3 : a1) : ((g & 2) ? a2 : a0);
    const float z = (float)av * fscale + xp_cur;
    const float s = 1.0f / (1.0f + __expf(-z));
    h = h * (1.0f - ALPHA_F) + s * ALPHA_F;

    *outp = h;  // every lane stores its row (coalesced 512 x 4B)

    uint32 bb = (uint32)(__float2int_rn(h * 127.f) & 255);
    uint32 c1 = bb | ((uint32)__shfl_xor((int)bb, 1) << 8);
    uint32 dw = c1 | ((uint32)__shfl_xor((int)c1, 2) << 16);
    if (g == 0) *((uint32*)&hq[cur ^ 1][144 * (o >> 5) + ((4 * o) & 127)]) = dw;
    __syncthreads();
    cur ^= 1;
    xp_cur = xp_nxt;
    xpp += BH;
    outp += BH;
  }

  if (t0 + ct == T_STEPS) {
    out[(size_t)T_STEPS * BATCH * HDIM + (size_t)b * HDIM + j] = h;
  }
}

// ---------------------------------------------------------------------------
extern "C" void kernel_launch(void* const* d_in, const int* in_sizes, int n_in,
                              void* d_out, int out_size, void* d_ws, size_t ws_size,
                              hipStream_t stream) {
  const float* x   = (const float*)d_in[0];
  const float* Win = (const float*)d_in[1];
  const float* Wh  = (const float*)d_in[2];
  const float* h0  = (const float*)d_in[3];
  float* out = (float*)d_out;
  float* xp  = (float*)d_ws;

  const size_t step_bytes = (size_t)BATCH * HDIM * sizeof(float);  // 128 KB
  int ct_max = (int)(ws_size / step_bytes);
  if (ct_max < 1) ct_max = 1;
  if (ct_max > T_STEPS) ct_max = T_STEPS;

  for (int t0 = 0; t0 < T_STEPS; t0 += ct_max) {
    const int ct = (T_STEPS - t0 < ct_max) ? (T_STEPS - t0) : ct_max;
    const int rows = ct * BATCH;
    const int nb = (rows + 127) / 128;
    hipLaunchKernelGGL(ctrnn_proj, dim3(nb), dim3(512), 0, stream,
                       x + (size_t)t0 * BATCH * IDIM, Win, xp, rows);
    hipLaunchKernelGGL(ctrnn_scan, dim3(BATCH), dim3(512), 0, stream,
                       xp, Wh, h0, out, t0, ct);
  }
}

// Round 11
// 931.156 us; speedup vs baseline: 2.1017x; 1.1846x over previous
//
// CTRNN MI355X — R11: |R|=8 slot-permuted reduce, DPP cross-lane, bank-perfect h layout
#include <hip/hip_runtime.h>

#define T_STEPS 1024
#define BATCH   64
#define IDIM    128
#define HDIM    512
#define ALPHA_F 0.02f

typedef _Float16 half2_t __attribute__((ext_vector_type(2)));
typedef unsigned int uint32;

__device__ __forceinline__ float dot2f(uint32 w, uint32 h, float acc) {
#if __has_builtin(__builtin_amdgcn_fdot2)
  return __builtin_amdgcn_fdot2(__builtin_bit_cast(half2_t, w),
                                __builtin_bit_cast(half2_t, h), acc, false);
#else
  half2_t a = __builtin_bit_cast(half2_t, w);
  half2_t b = __builtin_bit_cast(half2_t, h);
  return acc + (float)a.x * (float)b.x + (float)a.y * (float)b.y;
#endif
}

__device__ __forceinline__ uint32 pk2(float a, float b) {
  auto p = __builtin_amdgcn_cvt_pkrtz(a, b);
  return __builtin_bit_cast(uint32, p);
}

__device__ __forceinline__ int dot4i8(uint32 a, uint32 b, int c) {
#if __has_builtin(__builtin_amdgcn_sdot4)
  return __builtin_amdgcn_sdot4((int)a, (int)b, c, false);
#else
  int s = c;
  s += (int)(signed char)(a)        * (int)(signed char)(b);
  s += (int)(signed char)(a >> 8)   * (int)(signed char)(b >> 8);
  s += (int)(signed char)(a >> 16)  * (int)(signed char)(b >> 16);
  s += (int)(signed char)(a >> 24)  * (int)(signed char)(b >> 24);
  return s;
#endif
}

__device__ __forceinline__ uint32 pkq(float v0, float v1, float v2, float v3, float inv) {
  int i0 = __float2int_rn(v0 * inv), i1 = __float2int_rn(v1 * inv);
  int i2 = __float2int_rn(v2 * inv), i3 = __float2int_rn(v3 * inv);
  return (uint32)(i0 & 255) | ((uint32)(i1 & 255) << 8) |
         ((uint32)(i2 & 255) << 16) | ((uint32)(i3 & 255) << 24);
}

// cross-lane: xor1/xor2 via DPP quad_perm (VALU pipe), xor4 via ds_swizzle
__device__ __forceinline__ int dpp_xor1(int x) {
#if __has_builtin(__builtin_amdgcn_mov_dpp)
  return __builtin_amdgcn_mov_dpp(x, 0xB1, 0xF, 0xF, true);  // quad_perm [1,0,3,2]
#else
  return __shfl_xor(x, 1);
#endif
}
__device__ __forceinline__ int dpp_xor2(int x) {
#if __has_builtin(__builtin_amdgcn_mov_dpp)
  return __builtin_amdgcn_mov_dpp(x, 0x4E, 0xF, 0xF, true);  // quad_perm [2,3,0,1]
#else
  return __shfl_xor(x, 2);
#endif
}
__device__ __forceinline__ int swz_xor4(int x) {
#if __has_builtin(__builtin_amdgcn_ds_swizzle)
  return __builtin_amdgcn_ds_swizzle(x, 0x101F);  // BitMode xor=4, and=0x1F
#else
  return __shfl_xor(x, 4);
#endif
}
__device__ __forceinline__ float fxor1(float x) {
  return __builtin_bit_cast(float, dpp_xor1(__builtin_bit_cast(int, x)));
}
__device__ __forceinline__ float fxor2(float x) {
  return __builtin_bit_cast(float, dpp_xor2(__builtin_bit_cast(int, x)));
}
__device__ __forceinline__ float fxor4(float x) {
  return __builtin_bit_cast(float, swz_xor4(__builtin_bit_cast(int, x)));
}

// ---------------------------------------------------------------------------
// x_proj kernel: xp[m][j] = sum_i x[m][i] * Win[j][i]  (f16 dot2)
// ---------------------------------------------------------------------------
__global__ __launch_bounds__(512) void ctrnn_proj(
    const float* __restrict__ x,    // [rows][128]
    const float* __restrict__ Win,  // [512][128]
    float* __restrict__ xp,         // [rows][512]
    int rows) {
  const int j = threadIdx.x;
  __shared__ __attribute__((aligned(16))) uint32 xb[8][64];

  uint32 w[64];
  const float2* wr = (const float2*)(Win + (size_t)j * IDIM);
#pragma unroll
  for (int p = 0; p < 64; ++p) {
    float2 f = wr[p];
    w[p] = pk2(f.x, f.y);
  }

  const int m0 = blockIdx.x * 128;
  for (int it = 0; it < 16; ++it) {
    const int mb = m0 + it * 8;
    __syncthreads();
    if (j < 256) {
      const int r = j >> 5, q = j & 31;
      const int m = mb + r;
      float4 v = make_float4(0.f, 0.f, 0.f, 0.f);
      if (m < rows) v = *(const float4*)(x + (size_t)m * IDIM + q * 4);
      xb[r][2 * q]     = pk2(v.x, v.y);
      xb[r][2 * q + 1] = pk2(v.z, v.w);
    }
    __syncthreads();
#pragma unroll
    for (int r = 0; r < 8; ++r) {
      const int m = mb + r;
      if (m < rows) {
        const uint4* xv = (const uint4*)xb[r];
        float a0 = 0.f, a1 = 0.f, a2 = 0.f, a3 = 0.f;
#pragma unroll
        for (int c = 0; c < 16; ++c) {
          uint4 hx = xv[c];
          a0 = dot2f(w[4 * c + 0], hx.x, a0);
          a1 = dot2f(w[4 * c + 1], hx.y, a1);
          a2 = dot2f(w[4 * c + 2], hx.z, a2);
          a3 = dot2f(w[4 * c + 3], hx.w, a3);
        }
        xp[(size_t)m * HDIM + j] = (a0 + a1) + (a2 + a3);
      }
    }
  }
}

// ---------------------------------------------------------------------------
// scan kernel: 1 block/batch, 512 threads (2 waves/SIMD -> 128 arch VGPRs).
// thread j: g = j&7 (col-eighth, cols [64g,64g+64) = 16 i8 dwords),
//           o = j>>3 (rows 8o..8o+7). Lane finalizes row n = 8o+g == j.
// Acc slot i holds row 8o+(i XOR g): the 8-lane reduce becomes a 7-exchange
// tree with NO selects (keeps at even slots each round); xor1/xor2 via DPP
// (VALU pipe), xor4 via ds_swizzle. Own row lands in slot 0.
// h mirror: i8, row r at byte r+16*(r>>6): the 8 broadcast groups (base 80g)
// cover all 32 banks exactly once -> conflict-free b128 reads; writers
// (j%4==0) hit 16 distinct banks.
// ---------------------------------------------------------------------------
__global__ __launch_bounds__(512)
__attribute__((amdgpu_waves_per_eu(2, 2)))
void ctrnn_scan(
    const float* __restrict__ xp,  // [ct][BATCH][HDIM]
    const float* __restrict__ Wh,  // [512][512]
    const float* __restrict__ h0,  // [512]
    float* __restrict__ out,       // [T][B][H] then [B][H] final hidden
    int t0, int ct) {
  const int b = blockIdx.x;
  const int j = threadIdx.x;   // == output row n
  const int g = j & 7;
  const int o = j >> 3;

  __shared__ __attribute__((aligned(16))) unsigned char hq[2][640];

  // ---- pass 1: per-slot local absmax over 64 cols (slot i <-> row 8o+(i^g)) ----
  float m[8];
#pragma unroll
  for (int i = 0; i < 8; ++i) {
    const float4* wr = (const float4*)(Wh + (size_t)(8 * o + (i ^ g)) * HDIM + 64 * g);
    float mm = 0.f;
#pragma unroll
    for (int c = 0; c < 16; ++c) {
      float4 v = wr[c];
      mm = fmaxf(mm, fmaxf(fmaxf(fabsf(v.x), fabsf(v.y)), fmaxf(fabsf(v.z), fabsf(v.w))));
    }
    m[i] = mm;
  }
  // allreduce per ROW across the 8 lanes: partner's slot for my row i^g is i^k
  {
    float t[8];
#pragma unroll
    for (int i = 0; i < 8; ++i) t[i] = fmaxf(m[i], fxor1(m[i ^ 1]));
#pragma unroll
    for (int i = 0; i < 8; ++i) m[i] = fmaxf(t[i], fxor2(t[i ^ 2]));
#pragma unroll
    for (int i = 0; i < 8; ++i) t[i] = fmaxf(m[i], fxor4(m[i ^ 4]));
#pragma unroll
    for (int i = 0; i < 8; ++i) m[i] = t[i];
  }

  // ---- pass 2: quantize 8 row-slices (16 dwords each) into w[128] ----
  uint32 w[128];
#pragma unroll
  for (int i = 0; i < 8; ++i) {
    const float rm = m[i];
    const float inv = (rm > 0.f) ? 127.f / rm : 0.f;
    const float4* wr = (const float4*)(Wh + (size_t)(8 * o + (i ^ g)) * HDIM + 64 * g);
#pragma unroll
    for (int c = 0; c < 16; ++c) {
      float4 v = wr[c];
      w[i * 16 + c] = pkq(v.x, v.y, v.z, v.w, inv);
    }
  }
  const float fscale = m[0] * (1.f / (127.f * 127.f));  // own row == slot 0

  // ---- initial hidden: h (f32) in register, i8 mirror packed into hq[0] ----
  float h;
  if (t0 == 0) h = h0[j];
  else h = out[((size_t)(t0 - 1) * BATCH + b) * HDIM + j];
  {
    uint32 bb = (uint32)(__float2int_rn(h * 127.f) & 255);
    uint32 c1 = bb | ((uint32)dpp_xor1((int)bb) << 8);
    uint32 dw = c1 | ((uint32)dpp_xor2((int)c1) << 16);
    if ((j & 3) == 0) *((uint32*)&hq[0][j + 16 * (j >> 6)]) = dw;
  }
  __syncthreads();

  const float* xpp = xp + (size_t)b * HDIM + j;
  float* outp = out + ((size_t)t0 * BATCH + b) * HDIM + j;
  const size_t BH = (size_t)BATCH * HDIM;

  float xp_cur = xpp[0];
  int cur = 0;
  for (int t = 0; t < ct; ++t) {
    const float xp_nxt = xpp[(t + 1 < ct) ? BH : 0];

    const uint4* hb = (const uint4*)(&hq[cur][80 * g]);  // 4 x b128 = 64 h bytes
    int a0 = 0, a1 = 0, a2 = 0, a3 = 0, a4 = 0, a5 = 0, a6 = 0, a7 = 0;
#pragma unroll
    for (int c = 0; c < 4; ++c) {
      uint4 hv = hb[c];
      a0 = dot4i8(w[0 * 16 + 4 * c + 0], hv.x, a0);
      a0 = dot4i8(w[0 * 16 + 4 * c + 1], hv.y, a0);
      a0 = dot4i8(w[0 * 16 + 4 * c + 2], hv.z, a0);
      a0 = dot4i8(w[0 * 16 + 4 * c + 3], hv.w, a0);
      a1 = dot4i8(w[1 * 16 + 4 * c + 0], hv.x, a1);
      a1 = dot4i8(w[1 * 16 + 4 * c + 1], hv.y, a1);
      a1 = dot4i8(w[1 * 16 + 4 * c + 2], hv.z, a1);
      a1 = dot4i8(w[1 * 16 + 4 * c + 3], hv.w, a1);
      a2 = dot4i8(w[2 * 16 + 4 * c + 0], hv.x, a2);
      a2 = dot4i8(w[2 * 16 + 4 * c + 1], hv.y, a2);
      a2 = dot4i8(w[2 * 16 + 4 * c + 2], hv.z, a2);
      a2 = dot4i8(w[2 * 16 + 4 * c + 3], hv.w, a2);
      a3 = dot4i8(w[3 * 16 + 4 * c + 0], hv.x, a3);
      a3 = dot4i8(w[3 * 16 + 4 * c + 1], hv.y, a3);
      a3 = dot4i8(w[3 * 16 + 4 * c + 2], hv.z, a3);
      a3 = dot4i8(w[3 * 16 + 4 * c + 3], hv.w, a3);
      a4 = dot4i8(w[4 * 16 + 4 * c + 0], hv.x, a4);
      a4 = dot4i8(w[4 * 16 + 4 * c + 1], hv.y, a4);
      a4 = dot4i8(w[4 * 16 + 4 * c + 2], hv.z, a4);
      a4 = dot4i8(w[4 * 16 + 4 * c + 3], hv.w, a4);
      a5 = dot4i8(w[5 * 16 + 4 * c + 0], hv.x, a5);
      a5 = dot4i8(w[5 * 16 + 4 * c + 1], hv.y, a5);
      a5 = dot4i8(w[5 * 16 + 4 * c + 2], hv.z, a5);
      a5 = dot4i8(w[5 * 16 + 4 * c + 3], hv.w, a5);
      a6 = dot4i8(w[6 * 16 + 4 * c + 0], hv.x, a6);
      a6 = dot4i8(w[6 * 16 + 4 * c + 1], hv.y, a6);
      a6 = dot4i8(w[6 * 16 + 4 * c + 2], hv.z, a6);
      a6 = dot4i8(w[6 * 16 + 4 * c + 3], hv.w, a6);
      a7 = dot4i8(w[7 * 16 + 4 * c + 0], hv.x, a7);
      a7 = dot4i8(w[7 * 16 + 4 * c + 1], hv.y, a7);
      a7 = dot4i8(w[7 * 16 + 4 * c + 2], hv.z, a7);
      a7 = dot4i8(w[7 * 16 + 4 * c + 3], hv.w, a7);
    }
    // 7-exchange tree (keeps at even slots; own row ends in slot 0)
    const int q0 = a0 + dpp_xor1(a1);
    const int q1 = a2 + dpp_xor1(a3);
    const int q2 = a4 + dpp_xor1(a5);
    const int q3 = a6 + dpp_xor1(a7);
    const int r0 = q0 + dpp_xor2(q1);
    const int r1 = q2 + dpp_xor2(q3);
    const int res = r0 + swz_xor4(r1);

    const float z = (float)res * fscale + xp_cur;
    const float s = 1.0f / (1.0f + __expf(-z));
    h = h * (1.0f - ALPHA_F) + s * ALPHA_F;

    *outp = h;  // coalesced 512 x 4B

    uint32 bb = (uint32)(__float2int_rn(h * 127.f) & 255);
    uint32 c1 = bb | ((uint32)dpp_xor1((int)bb) << 8);
    uint32 dw = c1 | ((uint32)dpp_xor2((int)c1) << 16);
    if ((j & 3) == 0) *((uint32*)&hq[cur ^ 1][j + 16 * (j >> 6)]) = dw;
    __syncthreads();
    cur ^= 1;
    xp_cur = xp_nxt;
    xpp += BH;
    outp += BH;
  }

  if (t0 + ct == T_STEPS) {
    out[(size_t)T_STEPS * BATCH * HDIM + (size_t)b * HDIM + j] = h;
  }
}

// ---------------------------------------------------------------------------
extern "C" void kernel_launch(void* const* d_in, const int* in_sizes, int n_in,
                              void* d_out, int out_size, void* d_ws, size_t ws_size,
                              hipStream_t stream) {
  const float* x   = (const float*)d_in[0];
  const float* Win = (const float*)d_in[1];
  const float* Wh  = (const float*)d_in[2];
  const float* h0  = (const float*)d_in[3];
  float* out = (float*)d_out;
  float* xp  = (float*)d_ws;

  const size_t step_bytes = (size_t)BATCH * HDIM * sizeof(float);  // 128 KB
  int ct_max = (int)(ws_size / step_bytes);
  if (ct_max < 1) ct_max = 1;
  if (ct_max > T_STEPS) ct_max = T_STEPS;

  for (int t0 = 0; t0 < T_STEPS; t0 += ct_max) {
    const int ct = (T_STEPS - t0 < ct_max) ? (T_STEPS - t0) : ct_max;
    const int rows = ct * BATCH;
    const int nb = (rows + 127) / 128;
    hipLaunchKernelGGL(ctrnn_proj, dim3(nb), dim3(512), 0, stream,
                       x + (size_t)t0 * BATCH * IDIM, Win, xp, rows);
    hipLaunchKernelGGL(ctrnn_scan, dim3(BATCH), dim3(512), 0, stream,
                       xp, Wh, h0, out, t0, ct);
  }
}